// Round 1
// baseline (3452.767 us; speedup 1.0000x reference)
//
#include <hip/hip_runtime.h>

typedef float f4 __attribute__((ext_vector_type(4)));

constexpr int HIDDEN     = 128;
constexpr int OUT_EMB    = 256;
constexpr int OUT_CH     = 128;
constexpr int NUM_RADIAL = 6;
constexpr int NB         = 16;   // nodes per block in node kernel

// ---------------------------------------------------------------------------
// Edge phase: basis = rbf @ Wb^T ; msg = basis * x ; atomic scatter into agg
// Layout: 32 threads per edge, each thread owns 4 channels (float4 on x).
// ---------------------------------------------------------------------------
__global__ __launch_bounds__(256) void edge_scatter_kernel(
    const float* __restrict__ x, const float* __restrict__ rbf,
    const int* __restrict__ idx_i, const float* __restrict__ Wb,
    float* __restrict__ agg, long E)
{
    const int tid = threadIdx.x;
    const int c4  = tid & 31;      // channel group -> channels 4*c4 .. 4*c4+3
    const int eg  = tid >> 5;      // edge slot in block (0..7)

    // Preload my 4 rows of W_basis (24 floats) into registers, once.
    float wb[4][NUM_RADIAL];
#pragma unroll
    for (int j = 0; j < 4; ++j)
#pragma unroll
        for (int r = 0; r < NUM_RADIAL; ++r)
            wb[j][r] = Wb[(4 * c4 + j) * NUM_RADIAL + r];

    for (long e = (long)blockIdx.x * 8 + eg; e < E; e += (long)gridDim.x * 8) {
        const int node = idx_i[e];
        float rb[NUM_RADIAL];
#pragma unroll
        for (int r = 0; r < NUM_RADIAL; ++r) rb[r] = rbf[e * NUM_RADIAL + r];

        f4 xv = *(const f4*)(x + e * HIDDEN + 4 * c4);
        float* aggp = agg + (long)node * HIDDEN + 4 * c4;
#pragma unroll
        for (int j = 0; j < 4; ++j) {
            float b = 0.f;
#pragma unroll
            for (int r = 0; r < NUM_RADIAL; ++r) b = __builtin_fmaf(rb[r], wb[j][r], b);
            atomicAdd(aggp + j, b * xv[j]);
        }
    }
}

// ---------------------------------------------------------------------------
// Node phase: fused  agg @ Wp^T -> 3x silu(h@W^T+b) -> @ Wf^T
// 128 threads, 16 nodes per block. h kept in LDS as [channel][node] so the
// inner-loop LDS reads are wave-uniform (pure broadcast, conflict-free).
// Each thread: 2 output channels x 16 nodes register tile (32 f32 acc).
// ---------------------------------------------------------------------------
template <int IN, int OUT, bool BIAS_ACT>
__device__ inline void mlp_layer(const float* __restrict__ W,
                                 const float* __restrict__ bias,
                                 const float* hin, float* hout, int tid)
{
    // OUT==256: thread handles o0=tid and o1=tid+128.  OUT==128: only o0=tid.
    float acc0[NB], acc1[NB];
    float bb0 = 0.f, bb1 = 0.f;
    if (BIAS_ACT) {
        bb0 = bias[tid];
        if (OUT == 256) bb1 = bias[tid + 128];
    }
#pragma unroll
    for (int n = 0; n < NB; ++n) { acc0[n] = bb0; acc1[n] = bb1; }

    const float* w0p = W + (long)tid * IN;
    const float* w1p = W + (long)(tid + 128) * IN;

    for (int i0 = 0; i0 < IN; i0 += 4) {
        f4 w0 = *(const f4*)(w0p + i0);
        f4 w1;
        if (OUT == 256) w1 = *(const f4*)(w1p + i0);
#pragma unroll
        for (int k = 0; k < 4; ++k) {
#pragma unroll
            for (int nb = 0; nb < 4; ++nb) {
                f4 hv = *(const f4*)(hin + (i0 + k) * NB + nb * 4);
#pragma unroll
                for (int j = 0; j < 4; ++j) {
                    acc0[nb * 4 + j] = __builtin_fmaf(w0[k], hv[j], acc0[nb * 4 + j]);
                    if (OUT == 256)
                        acc1[nb * 4 + j] = __builtin_fmaf(w1[k], hv[j], acc1[nb * 4 + j]);
                }
            }
        }
    }

#pragma unroll
    for (int n = 0; n < NB; ++n) {
        float v0 = acc0[n];
        if (BIAS_ACT) v0 = v0 / (1.f + __expf(-v0));
        hout[tid * NB + n] = v0;
        if (OUT == 256) {
            float v1 = acc1[n];
            if (BIAS_ACT) v1 = v1 / (1.f + __expf(-v1));
            hout[(tid + 128) * NB + n] = v1;
        }
    }
}

__global__ __launch_bounds__(128) void node_mlp_kernel(
    const float* __restrict__ agg,
    const float* __restrict__ Wp,
    const float* __restrict__ W0, const float* __restrict__ b0,
    const float* __restrict__ W1, const float* __restrict__ b1,
    const float* __restrict__ W2, const float* __restrict__ b2,
    const float* __restrict__ Wf,
    float* __restrict__ out, int N)
{
    __shared__ float hA[OUT_EMB * NB];  // [channel][node]
    __shared__ float hB[OUT_EMB * NB];

    const int tid   = threadIdx.x;
    const int node0 = blockIdx.x * NB;

    // Load agg rows into hA as [i][n] (tid == channel i, coalesced on global).
    for (int n = 0; n < NB; ++n) {
        int node = node0 + n;
        float v = (node < N) ? agg[(long)node * HIDDEN + tid] : 0.f;
        hA[tid * NB + n] = v;
    }
    __syncthreads();

    mlp_layer<HIDDEN, OUT_EMB, false>(Wp, nullptr, hA, hB, tid);
    __syncthreads();
    mlp_layer<OUT_EMB, OUT_EMB, true>(W0, b0, hB, hA, tid);
    __syncthreads();
    mlp_layer<OUT_EMB, OUT_EMB, true>(W1, b1, hA, hB, tid);
    __syncthreads();
    mlp_layer<OUT_EMB, OUT_EMB, true>(W2, b2, hB, hA, tid);
    __syncthreads();

    // Final layer: IN=256 -> OUT=128, no bias/act, write straight to global.
    {
        float acc[NB];
#pragma unroll
        for (int n = 0; n < NB; ++n) acc[n] = 0.f;
        const float* wfp = Wf + (long)tid * OUT_EMB;
        for (int i0 = 0; i0 < OUT_EMB; i0 += 4) {
            f4 w = *(const f4*)(wfp + i0);
#pragma unroll
            for (int k = 0; k < 4; ++k) {
#pragma unroll
                for (int nb = 0; nb < 4; ++nb) {
                    f4 hv = *(const f4*)(hA + (i0 + k) * NB + nb * 4);
#pragma unroll
                    for (int j = 0; j < 4; ++j)
                        acc[nb * 4 + j] = __builtin_fmaf(w[k], hv[j], acc[nb * 4 + j]);
                }
            }
        }
#pragma unroll
        for (int n = 0; n < NB; ++n) {
            int node = node0 + n;
            if (node < N) out[(long)node * OUT_CH + tid] = acc[n];
        }
    }
}

// ---------------------------------------------------------------------------
extern "C" void kernel_launch(void* const* d_in, const int* in_sizes, int n_in,
                              void* d_out, int out_size, void* d_ws, size_t ws_size,
                              hipStream_t stream)
{
    // setup_inputs order: x, rbf, idx_i, num_nodes, W_basis, W_proj, W_final,
    //                     W0, b0, W1, b1, W2, b2
    const float* x   = (const float*)d_in[0];
    const float* rbf = (const float*)d_in[1];
    const int*   idx = (const int*)d_in[2];
    const float* Wb  = (const float*)d_in[4];
    const float* Wp  = (const float*)d_in[5];
    const float* Wf  = (const float*)d_in[6];
    const float* W0  = (const float*)d_in[7];
    const float* b0  = (const float*)d_in[8];
    const float* W1  = (const float*)d_in[9];
    const float* b1  = (const float*)d_in[10];
    const float* W2  = (const float*)d_in[11];
    const float* b2  = (const float*)d_in[12];

    const long E = (long)in_sizes[0] / HIDDEN;
    const int  N = out_size / OUT_CH;

    float* agg = (float*)d_ws;  // [N][HIDDEN] f32 = 25.6 MB

    hipMemsetAsync(agg, 0, (size_t)N * HIDDEN * sizeof(float), stream);

    edge_scatter_kernel<<<2048, 256, 0, stream>>>(x, rbf, idx, Wb, agg, E);

    node_mlp_kernel<<<(N + NB - 1) / NB, 128, 0, stream>>>(
        agg, Wp, W0, b0, W1, b1, W2, b2, Wf, (float*)d_out, N);
}

// Round 2
// 1279.190 us; speedup vs baseline: 2.6992x; 2.6992x over previous
//
#include <hip/hip_runtime.h>

typedef float f4 __attribute__((ext_vector_type(4)));
typedef float f2 __attribute__((ext_vector_type(2)));

constexpr int HIDDEN     = 128;
constexpr int OUT_EMB    = 256;
constexpr int OUT_CH     = 128;
constexpr int NUM_RADIAL = 6;
constexpr int NB         = 16;   // nodes per block in node kernel

// ---------------------------------------------------------------------------
// Phase 1a: histogram of edge target nodes
// ---------------------------------------------------------------------------
__global__ __launch_bounds__(256) void hist_kernel(const int* __restrict__ idx,
                                                   int* __restrict__ count, long E)
{
    long i = (long)blockIdx.x * blockDim.x + threadIdx.x;
    if (i < E) atomicAdd(&count[idx[i]], 1);
}

// ---------------------------------------------------------------------------
// Phase 1b: single-block exclusive scan over N counts -> start[N+1], cursor[N]
// ---------------------------------------------------------------------------
__global__ __launch_bounds__(1024) void scan_kernel(const int* __restrict__ count,
                                                    int* __restrict__ start,
                                                    int* __restrict__ cursor, int N)
{
    __shared__ int part[1024];
    const int tid   = threadIdx.x;
    const int chunk = (N + 1023) / 1024;
    const int lo    = tid * chunk;
    const int hi    = min(lo + chunk, N);

    int s = 0;
    for (int i = lo; i < hi; ++i) s += count[i];
    part[tid] = s;
    __syncthreads();

    for (int off = 1; off < 1024; off <<= 1) {
        int v = part[tid];
        int u = (tid >= off) ? part[tid - off] : 0;
        __syncthreads();
        part[tid] = v + u;
        __syncthreads();
    }

    int run = (tid > 0) ? part[tid - 1] : 0;  // exclusive prefix of my chunk
    for (int i = lo; i < hi; ++i) {
        start[i]  = run;
        cursor[i] = run;
        run += count[i];
    }
    if (tid == 1023) start[N] = part[1023];
}

// ---------------------------------------------------------------------------
// Phase 1c: scatter edge ids into CSR order
// ---------------------------------------------------------------------------
__global__ __launch_bounds__(256) void scatter_perm_kernel(const int* __restrict__ idx,
                                                           int* __restrict__ cursor,
                                                           int* __restrict__ perm, long E)
{
    long i = (long)blockIdx.x * blockDim.x + threadIdx.x;
    if (i < E) {
        int p = atomicAdd(&cursor[idx[i]], 1);
        perm[p] = (int)i;
    }
}

// ---------------------------------------------------------------------------
// Phase 1d: gather-reduce. One wave per node; lane owns channels 2l, 2l+1.
// Per edge: uniform perm/rbf loads, coalesced 512B x-row read, reg accumulate.
// No atomics.
// ---------------------------------------------------------------------------
__global__ __launch_bounds__(256) void gather_kernel(
    const float* __restrict__ x, const float* __restrict__ rbf,
    const float* __restrict__ Wb, const int* __restrict__ perm,
    const int* __restrict__ start, float* __restrict__ agg, int N)
{
    const int lane = threadIdx.x & 63;
    const int wid  = threadIdx.x >> 6;
    const int node = blockIdx.x * 4 + wid;
    if (node >= N) return;

    float wb0[NUM_RADIAL], wb1[NUM_RADIAL];
#pragma unroll
    for (int r = 0; r < NUM_RADIAL; ++r) {
        wb0[r] = Wb[(2 * lane)     * NUM_RADIAL + r];
        wb1[r] = Wb[(2 * lane + 1) * NUM_RADIAL + r];
    }

    const int j0 = start[node], j1 = start[node + 1];
    float a0 = 0.f, a1 = 0.f;

    int j = j0;
    for (; j + 2 <= j1; j += 2) {
        const int ea = perm[j], eb = perm[j + 1];
        const float* rba = rbf + (long)ea * NUM_RADIAL;
        const float* rbb = rbf + (long)eb * NUM_RADIAL;
        f2 xa = *(const f2*)(x + (long)ea * HIDDEN + 2 * lane);
        f2 xb = *(const f2*)(x + (long)eb * HIDDEN + 2 * lane);
        float ba0 = 0.f, ba1 = 0.f, bb0 = 0.f, bb1 = 0.f;
#pragma unroll
        for (int r = 0; r < NUM_RADIAL; ++r) {
            float ra = rba[r], rb = rbb[r];
            ba0 = __builtin_fmaf(ra, wb0[r], ba0);
            ba1 = __builtin_fmaf(ra, wb1[r], ba1);
            bb0 = __builtin_fmaf(rb, wb0[r], bb0);
            bb1 = __builtin_fmaf(rb, wb1[r], bb1);
        }
        a0 = __builtin_fmaf(ba0, xa[0], a0);
        a1 = __builtin_fmaf(ba1, xa[1], a1);
        a0 = __builtin_fmaf(bb0, xb[0], a0);
        a1 = __builtin_fmaf(bb1, xb[1], a1);
    }
    if (j < j1) {
        const int e = perm[j];
        const float* rb = rbf + (long)e * NUM_RADIAL;
        f2 xv = *(const f2*)(x + (long)e * HIDDEN + 2 * lane);
        float b0 = 0.f, b1 = 0.f;
#pragma unroll
        for (int r = 0; r < NUM_RADIAL; ++r) {
            float rv = rb[r];
            b0 = __builtin_fmaf(rv, wb0[r], b0);
            b1 = __builtin_fmaf(rv, wb1[r], b1);
        }
        a0 = __builtin_fmaf(b0, xv[0], a0);
        a1 = __builtin_fmaf(b1, xv[1], a1);
    }

    f2 out = {a0, a1};
    *(f2*)(agg + (long)node * HIDDEN + 2 * lane) = out;
}

// ---------------------------------------------------------------------------
// Node phase: fused  agg @ Wp^T -> 3x silu(h@W^T+b) -> @ Wf^T   (unchanged)
// ---------------------------------------------------------------------------
template <int IN, int OUT, bool BIAS_ACT>
__device__ inline void mlp_layer(const float* __restrict__ W,
                                 const float* __restrict__ bias,
                                 const float* hin, float* hout, int tid)
{
    float acc0[NB], acc1[NB];
    float bb0 = 0.f, bb1 = 0.f;
    if (BIAS_ACT) {
        bb0 = bias[tid];
        if (OUT == 256) bb1 = bias[tid + 128];
    }
#pragma unroll
    for (int n = 0; n < NB; ++n) { acc0[n] = bb0; acc1[n] = bb1; }

    const float* w0p = W + (long)tid * IN;
    const float* w1p = W + (long)(tid + 128) * IN;

    for (int i0 = 0; i0 < IN; i0 += 4) {
        f4 w0 = *(const f4*)(w0p + i0);
        f4 w1;
        if (OUT == 256) w1 = *(const f4*)(w1p + i0);
#pragma unroll
        for (int k = 0; k < 4; ++k) {
#pragma unroll
            for (int nb = 0; nb < 4; ++nb) {
                f4 hv = *(const f4*)(hin + (i0 + k) * NB + nb * 4);
#pragma unroll
                for (int j = 0; j < 4; ++j) {
                    acc0[nb * 4 + j] = __builtin_fmaf(w0[k], hv[j], acc0[nb * 4 + j]);
                    if (OUT == 256)
                        acc1[nb * 4 + j] = __builtin_fmaf(w1[k], hv[j], acc1[nb * 4 + j]);
                }
            }
        }
    }

#pragma unroll
    for (int n = 0; n < NB; ++n) {
        float v0 = acc0[n];
        if (BIAS_ACT) v0 = v0 / (1.f + __expf(-v0));
        hout[tid * NB + n] = v0;
        if (OUT == 256) {
            float v1 = acc1[n];
            if (BIAS_ACT) v1 = v1 / (1.f + __expf(-v1));
            hout[(tid + 128) * NB + n] = v1;
        }
    }
}

__global__ __launch_bounds__(128) void node_mlp_kernel(
    const float* __restrict__ agg,
    const float* __restrict__ Wp,
    const float* __restrict__ W0, const float* __restrict__ b0,
    const float* __restrict__ W1, const float* __restrict__ b1,
    const float* __restrict__ W2, const float* __restrict__ b2,
    const float* __restrict__ Wf,
    float* __restrict__ out, int N)
{
    __shared__ float hA[OUT_EMB * NB];  // [channel][node]
    __shared__ float hB[OUT_EMB * NB];

    const int tid   = threadIdx.x;
    const int node0 = blockIdx.x * NB;

    for (int n = 0; n < NB; ++n) {
        int node = node0 + n;
        float v = (node < N) ? agg[(long)node * HIDDEN + tid] : 0.f;
        hA[tid * NB + n] = v;
    }
    __syncthreads();

    mlp_layer<HIDDEN, OUT_EMB, false>(Wp, nullptr, hA, hB, tid);
    __syncthreads();
    mlp_layer<OUT_EMB, OUT_EMB, true>(W0, b0, hB, hA, tid);
    __syncthreads();
    mlp_layer<OUT_EMB, OUT_EMB, true>(W1, b1, hA, hB, tid);
    __syncthreads();
    mlp_layer<OUT_EMB, OUT_EMB, true>(W2, b2, hB, hA, tid);
    __syncthreads();

    {
        float acc[NB];
#pragma unroll
        for (int n = 0; n < NB; ++n) acc[n] = 0.f;
        const float* wfp = Wf + (long)tid * OUT_EMB;
        for (int i0 = 0; i0 < OUT_EMB; i0 += 4) {
            f4 w = *(const f4*)(wfp + i0);
#pragma unroll
            for (int k = 0; k < 4; ++k) {
#pragma unroll
                for (int nb = 0; nb < 4; ++nb) {
                    f4 hv = *(const f4*)(hA + (i0 + k) * NB + nb * 4);
#pragma unroll
                    for (int j = 0; j < 4; ++j)
                        acc[nb * 4 + j] = __builtin_fmaf(w[k], hv[j], acc[nb * 4 + j]);
                }
            }
        }
#pragma unroll
        for (int n = 0; n < NB; ++n) {
            int node = node0 + n;
            if (node < N) out[(long)node * OUT_CH + tid] = acc[n];
        }
    }
}

// ---------------------------------------------------------------------------
extern "C" void kernel_launch(void* const* d_in, const int* in_sizes, int n_in,
                              void* d_out, int out_size, void* d_ws, size_t ws_size,
                              hipStream_t stream)
{
    const float* x   = (const float*)d_in[0];
    const float* rbf = (const float*)d_in[1];
    const int*   idx = (const int*)d_in[2];
    const float* Wb  = (const float*)d_in[4];
    const float* Wp  = (const float*)d_in[5];
    const float* Wf  = (const float*)d_in[6];
    const float* W0  = (const float*)d_in[7];
    const float* b0  = (const float*)d_in[8];
    const float* W1  = (const float*)d_in[9];
    const float* b1  = (const float*)d_in[10];
    const float* W2  = (const float*)d_in[11];
    const float* b2  = (const float*)d_in[12];

    const long E = (long)in_sizes[0] / HIDDEN;
    const int  N = out_size / OUT_CH;

    // workspace layout
    float* agg   = (float*)d_ws;                   // N*HIDDEN f32
    int*   count = (int*)(agg + (long)N * HIDDEN); // N
    int*   startp= count + N;                      // N+1
    int*   cursor= startp + N + 1;                 // N
    int*   perm  = cursor + N;                     // E

    hipMemsetAsync(count, 0, (size_t)N * sizeof(int), stream);

    const int eb = (int)((E + 255) / 256);
    hist_kernel<<<eb, 256, 0, stream>>>(idx, count, E);
    scan_kernel<<<1, 1024, 0, stream>>>(count, startp, cursor, N);
    scatter_perm_kernel<<<eb, 256, 0, stream>>>(idx, cursor, perm, E);
    gather_kernel<<<(N + 3) / 4, 256, 0, stream>>>(x, rbf, Wb, perm, startp, agg, N);

    node_mlp_kernel<<<(N + NB - 1) / NB, 128, 0, stream>>>(
        agg, Wp, W0, b0, W1, b1, W2, b2, Wf, (float*)d_out, N);
}

// Round 3
// 767.284 us; speedup vs baseline: 4.5000x; 1.6672x over previous
//
#include <hip/hip_runtime.h>

typedef float f4 __attribute__((ext_vector_type(4)));
typedef float f2 __attribute__((ext_vector_type(2)));
typedef short bf16x8 __attribute__((ext_vector_type(8)));
typedef float f32x4 __attribute__((ext_vector_type(4)));

constexpr int HIDDEN     = 128;
constexpr int OUT_EMB    = 256;
constexpr int OUT_CH     = 128;
constexpr int NUM_RADIAL = 6;
constexpr int NBLK       = 64;   // nodes per block in MFMA node kernel

// ---------------- bf16 split helpers (RNE) ----------------
__device__ __forceinline__ unsigned short f2bf(float f) {
    unsigned int u = __float_as_uint(f);
    return (unsigned short)((u + 0x7FFFu + ((u >> 16) & 1u)) >> 16);
}
__device__ __forceinline__ float bf2f(unsigned short h) {
    return __uint_as_float(((unsigned int)h) << 16);
}

// ---------------------------------------------------------------------------
// Weight split: f32 -> bf16 hi + bf16 lo
// ---------------------------------------------------------------------------
__global__ __launch_bounds__(256) void split_kernel(const float* __restrict__ src,
                                                    unsigned short* __restrict__ hi,
                                                    unsigned short* __restrict__ lo, int n)
{
    int i = blockIdx.x * 256 + threadIdx.x;
    if (i < n) {
        float v = src[i];
        unsigned short h = f2bf(v);
        hi[i] = h;
        lo[i] = f2bf(v - bf2f(h));
    }
}

// ---------------------------------------------------------------------------
// Phase 1a: histogram of edge target nodes
// ---------------------------------------------------------------------------
__global__ __launch_bounds__(256) void hist_kernel(const int* __restrict__ idx,
                                                   int* __restrict__ count, long E)
{
    long i = (long)blockIdx.x * blockDim.x + threadIdx.x;
    if (i < E) atomicAdd(&count[idx[i]], 1);
}

// ---------------------------------------------------------------------------
// Phase 1b: single-block exclusive scan over N counts -> start[N+1], cursor[N]
// ---------------------------------------------------------------------------
__global__ __launch_bounds__(1024) void scan_kernel(const int* __restrict__ count,
                                                    int* __restrict__ start,
                                                    int* __restrict__ cursor, int N)
{
    __shared__ int part[1024];
    const int tid   = threadIdx.x;
    const int chunk = (N + 1023) / 1024;
    const int lo    = tid * chunk;
    const int hi    = min(lo + chunk, N);

    int s = 0;
    for (int i = lo; i < hi; ++i) s += count[i];
    part[tid] = s;
    __syncthreads();

    for (int off = 1; off < 1024; off <<= 1) {
        int v = part[tid];
        int u = (tid >= off) ? part[tid - off] : 0;
        __syncthreads();
        part[tid] = v + u;
        __syncthreads();
    }

    int run = (tid > 0) ? part[tid - 1] : 0;
    for (int i = lo; i < hi; ++i) {
        start[i]  = run;
        cursor[i] = run;
        run += count[i];
    }
    if (tid == 1023) start[N] = part[1023];
}

// ---------------------------------------------------------------------------
// Phase 1c: scatter edge ids into CSR order
// ---------------------------------------------------------------------------
__global__ __launch_bounds__(256) void scatter_perm_kernel(const int* __restrict__ idx,
                                                           int* __restrict__ cursor,
                                                           int* __restrict__ perm, long E)
{
    long i = (long)blockIdx.x * blockDim.x + threadIdx.x;
    if (i < E) {
        int p = atomicAdd(&cursor[idx[i]], 1);
        perm[p] = (int)i;
    }
}

// ---------------------------------------------------------------------------
// Phase 1d: gather-reduce (unchanged from round 2). One wave per node.
// ---------------------------------------------------------------------------
__global__ __launch_bounds__(256) void gather_kernel(
    const float* __restrict__ x, const float* __restrict__ rbf,
    const float* __restrict__ Wb, const int* __restrict__ perm,
    const int* __restrict__ start, float* __restrict__ agg, int N)
{
    const int lane = threadIdx.x & 63;
    const int wid  = threadIdx.x >> 6;
    const int node = blockIdx.x * 4 + wid;
    if (node >= N) return;

    float wb0[NUM_RADIAL], wb1[NUM_RADIAL];
#pragma unroll
    for (int r = 0; r < NUM_RADIAL; ++r) {
        wb0[r] = Wb[(2 * lane)     * NUM_RADIAL + r];
        wb1[r] = Wb[(2 * lane + 1) * NUM_RADIAL + r];
    }

    const int j0 = start[node], j1 = start[node + 1];
    float a0 = 0.f, a1 = 0.f;

    int j = j0;
    for (; j + 2 <= j1; j += 2) {
        const int ea = perm[j], eb = perm[j + 1];
        const float* rba = rbf + (long)ea * NUM_RADIAL;
        const float* rbb = rbf + (long)eb * NUM_RADIAL;
        f2 xa = *(const f2*)(x + (long)ea * HIDDEN + 2 * lane);
        f2 xb = *(const f2*)(x + (long)eb * HIDDEN + 2 * lane);
        float ba0 = 0.f, ba1 = 0.f, bb0 = 0.f, bb1 = 0.f;
#pragma unroll
        for (int r = 0; r < NUM_RADIAL; ++r) {
            float ra = rba[r], rb = rbb[r];
            ba0 = __builtin_fmaf(ra, wb0[r], ba0);
            ba1 = __builtin_fmaf(ra, wb1[r], ba1);
            bb0 = __builtin_fmaf(rb, wb0[r], bb0);
            bb1 = __builtin_fmaf(rb, wb1[r], bb1);
        }
        a0 = __builtin_fmaf(ba0, xa[0], a0);
        a1 = __builtin_fmaf(ba1, xa[1], a1);
        a0 = __builtin_fmaf(bb0, xb[0], a0);
        a1 = __builtin_fmaf(bb1, xb[1], a1);
    }
    if (j < j1) {
        const int e = perm[j];
        const float* rb = rbf + (long)e * NUM_RADIAL;
        f2 xv = *(const f2*)(x + (long)e * HIDDEN + 2 * lane);
        float b0 = 0.f, b1 = 0.f;
#pragma unroll
        for (int r = 0; r < NUM_RADIAL; ++r) {
            float rv = rb[r];
            b0 = __builtin_fmaf(rv, wb0[r], b0);
            b1 = __builtin_fmaf(rv, wb1[r], b1);
        }
        a0 = __builtin_fmaf(b0, xv[0], a0);
        a1 = __builtin_fmaf(b1, xv[1], a1);
    }

    f2 out = {a0, a1};
    *(f2*)(agg + (long)node * HIDDEN + 2 * lane) = out;
}

// ---------------------------------------------------------------------------
// Node phase, MFMA version. 64 nodes/block, 4 waves, wave owns OUT/4 cols.
// H tile in LDS as bf16 hi/lo, XOR-swizzled: idx = (node*256+col) ^ ((node&7)<<3).
// 3-term split GEMM: Hhi*Whi + Hlo*Whi + Hhi*Wlo, f32 accumulate.
// Fragment layout (16x16x32 bf16): A row=lane&15, k=(lane>>4)*8+j (8 contig);
//                                  B col=lane&15 (== W row), same k;
//                                  D col=lane&15, row=(lane>>4)*4+reg.
// ---------------------------------------------------------------------------
__device__ __forceinline__ int swz(int node, int col) {
    return (node * 256 + col) ^ ((node & 7) << 3);
}

template <int IN, int OUT, bool BIAS_ACT, bool LAST>
__device__ __forceinline__ void mfma_layer(
    const unsigned short* __restrict__ whi, const unsigned short* __restrict__ wlo,
    const float* __restrict__ bias,
    unsigned short* Hhi, unsigned short* Hlo,
    float* __restrict__ outp, int node0, int N, int w, int lane)
{
    const int lr = lane & 15;
    const int lg = lane >> 4;
    constexpr int NT = OUT / 64;      // n-tiles per wave
    const int wbase = w * (OUT / 4);  // this wave's first out-col

    f32x4 acc[4][NT];
#pragma unroll
    for (int nt = 0; nt < NT; ++nt) {
        float bb = 0.f;
        if constexpr (BIAS_ACT) bb = bias[wbase + nt * 16 + lr];
#pragma unroll
        for (int mt = 0; mt < 4; ++mt) {
            acc[mt][nt][0] = bb; acc[mt][nt][1] = bb;
            acc[mt][nt][2] = bb; acc[mt][nt][3] = bb;
        }
    }

    for (int ks = 0; ks < IN / 32; ++ks) {
        const int k0 = ks * 32 + lg * 8;
        bf16x8 ah[4], al[4];
#pragma unroll
        for (int mt = 0; mt < 4; ++mt) {
            const int node = mt * 16 + lr;
            const int idx  = swz(node, k0);
            ah[mt] = *(const bf16x8*)&Hhi[idx];
            al[mt] = *(const bf16x8*)&Hlo[idx];
        }
#pragma unroll
        for (int nt = 0; nt < NT; ++nt) {
            const long wrow = (long)(wbase + nt * 16 + lr) * IN + k0;
            bf16x8 bh = *(const bf16x8*)&whi[wrow];
            bf16x8 bl = *(const bf16x8*)&wlo[wrow];
#pragma unroll
            for (int mt = 0; mt < 4; ++mt) {
                acc[mt][nt] = __builtin_amdgcn_mfma_f32_16x16x32_bf16(ah[mt], bh, acc[mt][nt], 0, 0, 0);
                acc[mt][nt] = __builtin_amdgcn_mfma_f32_16x16x32_bf16(al[mt], bh, acc[mt][nt], 0, 0, 0);
                acc[mt][nt] = __builtin_amdgcn_mfma_f32_16x16x32_bf16(ah[mt], bl, acc[mt][nt], 0, 0, 0);
            }
        }
    }

    __syncthreads();  // all waves done READING H before anyone overwrites it

#pragma unroll
    for (int mt = 0; mt < 4; ++mt) {
#pragma unroll
        for (int nt = 0; nt < NT; ++nt) {
#pragma unroll
            for (int r = 0; r < 4; ++r) {
                float v = acc[mt][nt][r];
                if constexpr (BIAS_ACT) v = v / (1.f + __expf(-v));
                const int node = mt * 16 + lg * 4 + r;
                const int col  = wbase + nt * 16 + lr;
                if constexpr (LAST) {
                    if (node0 + node < N) outp[(long)(node0 + node) * OUT + col] = v;
                } else {
                    unsigned short hi = f2bf(v);
                    unsigned short lo = f2bf(v - bf2f(hi));
                    const int idx = swz(node, col);
                    Hhi[idx] = hi;
                    Hlo[idx] = lo;
                }
            }
        }
    }
    if constexpr (!LAST) __syncthreads();
}

__global__ __launch_bounds__(256, 2) void node_mlp_mfma_kernel(
    const float* __restrict__ agg,
    const unsigned short* __restrict__ WpHi, const unsigned short* __restrict__ WpLo,
    const unsigned short* __restrict__ W0Hi, const unsigned short* __restrict__ W0Lo,
    const float* __restrict__ b0,
    const unsigned short* __restrict__ W1Hi, const unsigned short* __restrict__ W1Lo,
    const float* __restrict__ b1,
    const unsigned short* __restrict__ W2Hi, const unsigned short* __restrict__ W2Lo,
    const float* __restrict__ b2,
    const unsigned short* __restrict__ WfHi, const unsigned short* __restrict__ WfLo,
    float* __restrict__ out, int N)
{
    __shared__ unsigned short Hhi[NBLK * 256];
    __shared__ unsigned short Hlo[NBLK * 256];

    const int tid   = threadIdx.x;
    const int w     = tid >> 6;
    const int lane  = tid & 63;
    const int node0 = blockIdx.x * NBLK;

    // Load agg [64 x 128] f32 -> split into LDS (coalesced global reads).
#pragma unroll
    for (int i = 0; i < (NBLK * HIDDEN) / 256; ++i) {
        const int e    = i * 256 + tid;
        const int node = e >> 7;
        const int col  = e & 127;
        float v = 0.f;
        if (node0 + node < N) v = agg[(long)(node0 + node) * HIDDEN + col];
        unsigned short hi = f2bf(v);
        unsigned short lo = f2bf(v - bf2f(hi));
        const int idx = swz(node, col);
        Hhi[idx] = hi;
        Hlo[idx] = lo;
    }
    __syncthreads();

    mfma_layer<HIDDEN,  OUT_EMB, false, false>(WpHi, WpLo, nullptr, Hhi, Hlo, nullptr, node0, N, w, lane);
    mfma_layer<OUT_EMB, OUT_EMB, true,  false>(W0Hi, W0Lo, b0,      Hhi, Hlo, nullptr, node0, N, w, lane);
    mfma_layer<OUT_EMB, OUT_EMB, true,  false>(W1Hi, W1Lo, b1,      Hhi, Hlo, nullptr, node0, N, w, lane);
    mfma_layer<OUT_EMB, OUT_EMB, true,  false>(W2Hi, W2Lo, b2,      Hhi, Hlo, nullptr, node0, N, w, lane);
    mfma_layer<OUT_EMB, OUT_CH,  false, true >(WfHi, WfLo, nullptr, Hhi, Hlo, out,     node0, N, w, lane);
}

// ---------------------------------------------------------------------------
extern "C" void kernel_launch(void* const* d_in, const int* in_sizes, int n_in,
                              void* d_out, int out_size, void* d_ws, size_t ws_size,
                              hipStream_t stream)
{
    const float* x   = (const float*)d_in[0];
    const float* rbf = (const float*)d_in[1];
    const int*   idx = (const int*)d_in[2];
    const float* Wb  = (const float*)d_in[4];
    const float* Wp  = (const float*)d_in[5];
    const float* Wf  = (const float*)d_in[6];
    const float* W0  = (const float*)d_in[7];
    const float* b0  = (const float*)d_in[8];
    const float* W1  = (const float*)d_in[9];
    const float* b1  = (const float*)d_in[10];
    const float* W2  = (const float*)d_in[11];
    const float* b2  = (const float*)d_in[12];

    const long E = (long)in_sizes[0] / HIDDEN;
    const int  N = out_size / OUT_CH;

    // workspace layout
    float* agg    = (float*)d_ws;                    // N*HIDDEN f32
    int*   count  = (int*)(agg + (long)N * HIDDEN);  // N
    int*   startp = count + N;                       // N+1
    int*   cursor = startp + N + 1;                  // N
    int*   perm   = cursor + N;                      // E
    // bf16 split weights after perm, 16B-aligned
    uintptr_t p = (uintptr_t)(perm + E);
    p = (p + 15) & ~(uintptr_t)15;
    unsigned short* WpHi = (unsigned short*)p;       // 32768
    unsigned short* WpLo = WpHi + 32768;
    unsigned short* W0Hi = WpLo + 32768;             // 65536
    unsigned short* W0Lo = W0Hi + 65536;
    unsigned short* W1Hi = W0Lo + 65536;
    unsigned short* W1Lo = W1Hi + 65536;
    unsigned short* W2Hi = W1Lo + 65536;
    unsigned short* W2Lo = W2Hi + 65536;
    unsigned short* WfHi = W2Lo + 65536;             // 32768
    unsigned short* WfLo = WfHi + 32768;

    hipMemsetAsync(count, 0, (size_t)N * sizeof(int), stream);

    split_kernel<<<(32768 + 255) / 256, 256, 0, stream>>>(Wp, WpHi, WpLo, 32768);
    split_kernel<<<(65536 + 255) / 256, 256, 0, stream>>>(W0, W0Hi, W0Lo, 65536);
    split_kernel<<<(65536 + 255) / 256, 256, 0, stream>>>(W1, W1Hi, W1Lo, 65536);
    split_kernel<<<(65536 + 255) / 256, 256, 0, stream>>>(W2, W2Hi, W2Lo, 65536);
    split_kernel<<<(32768 + 255) / 256, 256, 0, stream>>>(Wf, WfHi, WfLo, 32768);

    const int eb = (int)((E + 255) / 256);
    hist_kernel<<<eb, 256, 0, stream>>>(idx, count, E);
    scan_kernel<<<1, 1024, 0, stream>>>(count, startp, cursor, N);
    scatter_perm_kernel<<<eb, 256, 0, stream>>>(idx, cursor, perm, E);
    gather_kernel<<<(N + 3) / 4, 256, 0, stream>>>(x, rbf, Wb, perm, startp, agg, N);

    node_mlp_mfma_kernel<<<(N + NBLK - 1) / NBLK, 256, 0, stream>>>(
        agg, WpHi, WpLo, W0Hi, W0Lo, b0, W1Hi, W1Lo, b1, W2Hi, W2Lo, b2,
        WfHi, WfLo, (float*)d_out, N);
}

// Round 4
// 710.033 us; speedup vs baseline: 4.8628x; 1.0806x over previous
//
#include <hip/hip_runtime.h>

typedef float f4 __attribute__((ext_vector_type(4)));
typedef float f2 __attribute__((ext_vector_type(2)));
typedef short bf16x8 __attribute__((ext_vector_type(8)));
typedef float f32x4 __attribute__((ext_vector_type(4)));

constexpr int HIDDEN     = 128;
constexpr int OUT_EMB    = 256;
constexpr int OUT_CH     = 128;
constexpr int NUM_RADIAL = 6;
constexpr int NBLK       = 64;   // nodes per block in MFMA node kernel

// ---------------- bf16 split helpers (RNE) ----------------
__device__ __forceinline__ unsigned short f2bf(float f) {
    unsigned int u = __float_as_uint(f);
    return (unsigned short)((u + 0x7FFFu + ((u >> 16) & 1u)) >> 16);
}
__device__ __forceinline__ float bf2f(unsigned short h) {
    return __uint_as_float(((unsigned int)h) << 16);
}

// ---------------------------------------------------------------------------
__global__ __launch_bounds__(256) void zero_kernel(int* __restrict__ p, int n)
{
    int i = blockIdx.x * 256 + threadIdx.x;
    if (i < n) p[i] = 0;
}

// ---------------------------------------------------------------------------
// Weight split: f32 -> bf16 hi + bf16 lo
// ---------------------------------------------------------------------------
__global__ __launch_bounds__(256) void split_kernel(const float* __restrict__ src,
                                                    unsigned short* __restrict__ hi,
                                                    unsigned short* __restrict__ lo, int n)
{
    int i = blockIdx.x * 256 + threadIdx.x;
    if (i < n) {
        float v = src[i];
        unsigned short h = f2bf(v);
        hi[i] = h;
        lo[i] = f2bf(v - bf2f(h));
    }
}

// ---------------------------------------------------------------------------
// Phase 1a: histogram of edge target nodes
// ---------------------------------------------------------------------------
__global__ __launch_bounds__(256) void hist_kernel(const int* __restrict__ idx,
                                                   int* __restrict__ count, long E)
{
    long i = (long)blockIdx.x * blockDim.x + threadIdx.x;
    if (i < E) atomicAdd(&count[idx[i]], 1);
}

// ---------------------------------------------------------------------------
// Phase 1b: single-block exclusive scan over N counts -> start[N+1], cursor[N]
// ---------------------------------------------------------------------------
__global__ __launch_bounds__(1024) void scan_kernel(const int* __restrict__ count,
                                                    int* __restrict__ start,
                                                    int* __restrict__ cursor, int N)
{
    __shared__ int part[1024];
    const int tid   = threadIdx.x;
    const int chunk = (N + 1023) / 1024;
    const int lo    = tid * chunk;
    const int hi    = min(lo + chunk, N);

    int s = 0;
    for (int i = lo; i < hi; ++i) s += count[i];
    part[tid] = s;
    __syncthreads();

    for (int off = 1; off < 1024; off <<= 1) {
        int v = part[tid];
        int u = (tid >= off) ? part[tid - off] : 0;
        __syncthreads();
        part[tid] = v + u;
        __syncthreads();
    }

    int run = (tid > 0) ? part[tid - 1] : 0;
    for (int i = lo; i < hi; ++i) {
        start[i]  = run;
        cursor[i] = run;
        run += count[i];
    }
    if (tid == 1023) start[N] = part[1023];
}

// ---------------------------------------------------------------------------
// Phase 1c: scatter edge ids into CSR order
// ---------------------------------------------------------------------------
__global__ __launch_bounds__(256) void scatter_perm_kernel(const int* __restrict__ idx,
                                                           int* __restrict__ cursor,
                                                           int* __restrict__ perm, long E)
{
    long i = (long)blockIdx.x * blockDim.x + threadIdx.x;
    if (i < E) {
        int p = atomicAdd(&cursor[idx[i]], 1);
        perm[p] = (int)i;
    }
}

// ---------------------------------------------------------------------------
// Phase 1d: gather-reduce, ILP version. One wave per node.
// Half-wave (32 lanes) owns one edge at a time; lane owns 4 channels (f4).
// 4 edges in flight per wave (2 halves x unroll 2). Cross-half reduce at end.
// ---------------------------------------------------------------------------
__device__ __forceinline__ void edge_accum(const float* __restrict__ x,
                                           const float* __restrict__ rbf,
                                           const float wb[4][NUM_RADIAL],
                                           int e, int l, f4& acc)
{
    const float* rp = rbf + (long)e * NUM_RADIAL;
    f2 r01 = *(const f2*)(rp);
    f2 r23 = *(const f2*)(rp + 2);
    f2 r45 = *(const f2*)(rp + 4);
    f4 xv  = *(const f4*)(x + (long)e * HIDDEN + 4 * l);
    float rb[NUM_RADIAL] = {r01[0], r01[1], r23[0], r23[1], r45[0], r45[1]};
#pragma unroll
    for (int c = 0; c < 4; ++c) {
        float b = 0.f;
#pragma unroll
        for (int r = 0; r < NUM_RADIAL; ++r) b = __builtin_fmaf(rb[r], wb[c][r], b);
        acc[c] = __builtin_fmaf(b, xv[c], acc[c]);
    }
}

__global__ __launch_bounds__(256) void gather_kernel(
    const float* __restrict__ x, const float* __restrict__ rbf,
    const float* __restrict__ Wb, const int* __restrict__ perm,
    const int* __restrict__ start, float* __restrict__ agg, int N)
{
    const int lane = threadIdx.x & 63;
    const int half = lane >> 5;
    const int l    = lane & 31;          // channel group: 4l..4l+3
    const int wid  = threadIdx.x >> 6;
    const int node = blockIdx.x * 4 + wid;
    if (node >= N) return;

    float wb[4][NUM_RADIAL];
#pragma unroll
    for (int c = 0; c < 4; ++c)
#pragma unroll
        for (int r = 0; r < NUM_RADIAL; ++r)
            wb[c][r] = Wb[(4 * l + c) * NUM_RADIAL + r];

    const int j0 = start[node], j1 = start[node + 1];
    f4 acc = {0.f, 0.f, 0.f, 0.f};

    int j = j0 + half;                    // this half's edge stream (stride 2)
    for (; j + 2 < j1; j += 4) {          // 2 edges per half in flight
        const int ea = perm[j];
        const int eb = perm[j + 2];
        edge_accum(x, rbf, wb, ea, l, acc);
        edge_accum(x, rbf, wb, eb, l, acc);
    }
    if (j < j1) edge_accum(x, rbf, wb, perm[j], l, acc);

    // combine the two halves
#pragma unroll
    for (int c = 0; c < 4; ++c) acc[c] += __shfl_xor(acc[c], 32);

    if (half == 0)
        *(f4*)(agg + (long)node * HIDDEN + 4 * l) = acc;
}

// ---------------------------------------------------------------------------
// Node phase, MFMA version (unchanged from round 3).
// ---------------------------------------------------------------------------
__device__ __forceinline__ int swz(int node, int col) {
    return (node * 256 + col) ^ ((node & 7) << 3);
}

template <int IN, int OUT, bool BIAS_ACT, bool LAST>
__device__ __forceinline__ void mfma_layer(
    const unsigned short* __restrict__ whi, const unsigned short* __restrict__ wlo,
    const float* __restrict__ bias,
    unsigned short* Hhi, unsigned short* Hlo,
    float* __restrict__ outp, int node0, int N, int w, int lane)
{
    const int lr = lane & 15;
    const int lg = lane >> 4;
    constexpr int NT = OUT / 64;
    const int wbase = w * (OUT / 4);

    f32x4 acc[4][NT];
#pragma unroll
    for (int nt = 0; nt < NT; ++nt) {
        float bb = 0.f;
        if constexpr (BIAS_ACT) bb = bias[wbase + nt * 16 + lr];
#pragma unroll
        for (int mt = 0; mt < 4; ++mt) {
            acc[mt][nt][0] = bb; acc[mt][nt][1] = bb;
            acc[mt][nt][2] = bb; acc[mt][nt][3] = bb;
        }
    }

    for (int ks = 0; ks < IN / 32; ++ks) {
        const int k0 = ks * 32 + lg * 8;
        bf16x8 ah[4], al[4];
#pragma unroll
        for (int mt = 0; mt < 4; ++mt) {
            const int node = mt * 16 + lr;
            const int idx  = swz(node, k0);
            ah[mt] = *(const bf16x8*)&Hhi[idx];
            al[mt] = *(const bf16x8*)&Hlo[idx];
        }
#pragma unroll
        for (int nt = 0; nt < NT; ++nt) {
            const long wrow = (long)(wbase + nt * 16 + lr) * IN + k0;
            bf16x8 bh = *(const bf16x8*)&whi[wrow];
            bf16x8 bl = *(const bf16x8*)&wlo[wrow];
#pragma unroll
            for (int mt = 0; mt < 4; ++mt) {
                acc[mt][nt] = __builtin_amdgcn_mfma_f32_16x16x32_bf16(ah[mt], bh, acc[mt][nt], 0, 0, 0);
                acc[mt][nt] = __builtin_amdgcn_mfma_f32_16x16x32_bf16(al[mt], bh, acc[mt][nt], 0, 0, 0);
                acc[mt][nt] = __builtin_amdgcn_mfma_f32_16x16x32_bf16(ah[mt], bl, acc[mt][nt], 0, 0, 0);
            }
        }
    }

    __syncthreads();

#pragma unroll
    for (int mt = 0; mt < 4; ++mt) {
#pragma unroll
        for (int nt = 0; nt < NT; ++nt) {
#pragma unroll
            for (int r = 0; r < 4; ++r) {
                float v = acc[mt][nt][r];
                if constexpr (BIAS_ACT) v = v / (1.f + __expf(-v));
                const int node = mt * 16 + lg * 4 + r;
                const int col  = wbase + nt * 16 + lr;
                if constexpr (LAST) {
                    if (node0 + node < N) outp[(long)(node0 + node) * OUT + col] = v;
                } else {
                    unsigned short hi = f2bf(v);
                    unsigned short lo = f2bf(v - bf2f(hi));
                    const int idx = swz(node, col);
                    Hhi[idx] = hi;
                    Hlo[idx] = lo;
                }
            }
        }
    }
    if constexpr (!LAST) __syncthreads();
}

__global__ __launch_bounds__(256, 2) void node_mlp_mfma_kernel(
    const float* __restrict__ agg,
    const unsigned short* __restrict__ WpHi, const unsigned short* __restrict__ WpLo,
    const unsigned short* __restrict__ W0Hi, const unsigned short* __restrict__ W0Lo,
    const float* __restrict__ b0,
    const unsigned short* __restrict__ W1Hi, const unsigned short* __restrict__ W1Lo,
    const float* __restrict__ b1,
    const unsigned short* __restrict__ W2Hi, const unsigned short* __restrict__ W2Lo,
    const float* __restrict__ b2,
    const unsigned short* __restrict__ WfHi, const unsigned short* __restrict__ WfLo,
    float* __restrict__ out, int N)
{
    __shared__ unsigned short Hhi[NBLK * 256];
    __shared__ unsigned short Hlo[NBLK * 256];

    const int tid   = threadIdx.x;
    const int w     = tid >> 6;
    const int lane  = tid & 63;
    const int node0 = blockIdx.x * NBLK;

#pragma unroll
    for (int i = 0; i < (NBLK * HIDDEN) / 256; ++i) {
        const int e    = i * 256 + tid;
        const int node = e >> 7;
        const int col  = e & 127;
        float v = 0.f;
        if (node0 + node < N) v = agg[(long)(node0 + node) * HIDDEN + col];
        unsigned short hi = f2bf(v);
        unsigned short lo = f2bf(v - bf2f(hi));
        const int idx = swz(node, col);
        Hhi[idx] = hi;
        Hlo[idx] = lo;
    }
    __syncthreads();

    mfma_layer<HIDDEN,  OUT_EMB, false, false>(WpHi, WpLo, nullptr, Hhi, Hlo, nullptr, node0, N, w, lane);
    mfma_layer<OUT_EMB, OUT_EMB, true,  false>(W0Hi, W0Lo, b0,      Hhi, Hlo, nullptr, node0, N, w, lane);
    mfma_layer<OUT_EMB, OUT_EMB, true,  false>(W1Hi, W1Lo, b1,      Hhi, Hlo, nullptr, node0, N, w, lane);
    mfma_layer<OUT_EMB, OUT_EMB, true,  false>(W2Hi, W2Lo, b2,      Hhi, Hlo, nullptr, node0, N, w, lane);
    mfma_layer<OUT_EMB, OUT_CH,  false, true >(WfHi, WfLo, nullptr, Hhi, Hlo, out,     node0, N, w, lane);
}

// ---------------------------------------------------------------------------
extern "C" void kernel_launch(void* const* d_in, const int* in_sizes, int n_in,
                              void* d_out, int out_size, void* d_ws, size_t ws_size,
                              hipStream_t stream)
{
    const float* x   = (const float*)d_in[0];
    const float* rbf = (const float*)d_in[1];
    const int*   idx = (const int*)d_in[2];
    const float* Wb  = (const float*)d_in[4];
    const float* Wp  = (const float*)d_in[5];
    const float* Wf  = (const float*)d_in[6];
    const float* W0  = (const float*)d_in[7];
    const float* b0  = (const float*)d_in[8];
    const float* W1  = (const float*)d_in[9];
    const float* b1  = (const float*)d_in[10];
    const float* W2  = (const float*)d_in[11];
    const float* b2  = (const float*)d_in[12];

    const long E = (long)in_sizes[0] / HIDDEN;
    const int  N = out_size / OUT_CH;

    // workspace layout
    float* agg    = (float*)d_ws;                    // N*HIDDEN f32
    int*   count  = (int*)(agg + (long)N * HIDDEN);  // N
    int*   startp = count + N;                       // N+1
    int*   cursor = startp + N + 1;                  // N
    int*   perm   = cursor + N;                      // E
    uintptr_t p = (uintptr_t)(perm + E);
    p = (p + 15) & ~(uintptr_t)15;
    unsigned short* WpHi = (unsigned short*)p;       // 32768
    unsigned short* WpLo = WpHi + 32768;
    unsigned short* W0Hi = WpLo + 32768;             // 65536
    unsigned short* W0Lo = W0Hi + 65536;
    unsigned short* W1Hi = W0Lo + 65536;
    unsigned short* W1Lo = W1Hi + 65536;
    unsigned short* W2Hi = W1Lo + 65536;
    unsigned short* W2Lo = W2Hi + 65536;
    unsigned short* WfHi = W2Lo + 65536;             // 32768
    unsigned short* WfLo = WfHi + 32768;

    zero_kernel<<<(N + 255) / 256, 256, 0, stream>>>(count, N);

    split_kernel<<<(32768 + 255) / 256, 256, 0, stream>>>(Wp, WpHi, WpLo, 32768);
    split_kernel<<<(65536 + 255) / 256, 256, 0, stream>>>(W0, W0Hi, W0Lo, 65536);
    split_kernel<<<(65536 + 255) / 256, 256, 0, stream>>>(W1, W1Hi, W1Lo, 65536);
    split_kernel<<<(65536 + 255) / 256, 256, 0, stream>>>(W2, W2Hi, W2Lo, 65536);
    split_kernel<<<(32768 + 255) / 256, 256, 0, stream>>>(Wf, WfHi, WfLo, 32768);

    const int eb = (int)((E + 255) / 256);
    hist_kernel<<<eb, 256, 0, stream>>>(idx, count, E);
    scan_kernel<<<1, 1024, 0, stream>>>(count, startp, cursor, N);
    scatter_perm_kernel<<<eb, 256, 0, stream>>>(idx, cursor, perm, E);
    gather_kernel<<<(N + 3) / 4, 256, 0, stream>>>(x, rbf, Wb, perm, startp, agg, N);

    node_mlp_mfma_kernel<<<(N + NBLK - 1) / NBLK, 256, 0, stream>>>(
        agg, WpHi, WpLo, W0Hi, W0Lo, b0, W1Hi, W1Lo, b1, W2Hi, W2Lo, b2,
        WfHi, WfLo, (float*)d_out, N);
}